// Round 16
// baseline (134.202 us; speedup 1.0000x reference)
//
#include <hip/hip_runtime.h>
#include <cstddef>

#define NN 3072
#define RR 16
#define NB 16
#define FILL_BLOCKS 256
#define FILL_ITERS 576   // quads/block = (NN*NN*4)/FILL_BLOCKS / 256 lanes = 576

typedef float f32x4 __attribute__((ext_vector_type(4)));

// Prologue: key[i] = valid ? batch[i] : -1, plus batch row boundaries
// start[b] = first row with batch >= b (batch sorted). start[NB]=NN.
__global__ void frd_prep_kernel(const int* __restrict__ cls,
                                const int* __restrict__ batch,
                                int* __restrict__ key,
                                int* __restrict__ start) {
    int t = blockIdx.x * blockDim.x + threadIdx.x;
    if (t < NN) {
        int c = cls[t];
        int b = batch[t];
        key[t] = (c != 24 && c != 25 && c != 26) ? b : -1;
        int prev = (t == 0) ? -1 : batch[t - 1];
        for (int bb = prev + 1; bb <= b; ++bb) start[bb] = t;
        if (t == NN - 1)
            for (int bb = b + 1; bb <= NB; ++bb) start[bb] = NN;
    }
}

// Phase 1: pure NT fill, 256 blocks, BLOCK-CONTIGUOUS partitions (A/B vs
// R14's grid-stride): block b owns a sequential 2.36 MB slab, advancing 4 KB
// per iteration -> each block's address stream is strictly sequential, giving
// the HBM controllers row-sequential per-channel sub-streams.
__global__ __launch_bounds__(256)
void frd_fill_kernel(float* __restrict__ out) {
    const float d0 = ((threadIdx.x & 3) == 0) ? 1.0f : 0.0f;
    const f32x4 r = {d0, 0.0f, 0.0f, 0.0f};
    // block slab: FILL_ITERS * 256 quads, walked 256 quads (4 KB) at a time
    float* p = out + ((size_t)blockIdx.x * FILL_ITERS * 256 + threadIdx.x) * 4;
#pragma unroll 8
    for (int it = 0; it < FILL_ITERS; ++it) {
        __builtin_nontemporal_store(r, reinterpret_cast<f32x4*>(p));
        p += 256 * 4;                      // next 4 KB chunk of this block's slab
    }
}

// Phase 3: overwrite true pairs only. One block per row i (exit if key
// invalid). 4 lanes per pair (lane q writes quad q) -> each written pair is
// one full 64 B line, coalesced across the wave. Sweeps row i's batch range.
__global__ __launch_bounds__(256)
void frd_diag_kernel(const float* __restrict__ z1,
                     const float* __restrict__ z2,
                     const float* __restrict__ seg,
                     const int* __restrict__ key,
                     const int* __restrict__ start,
                     float* __restrict__ out) {
    const int i = blockIdx.x;
    const int ki = key[i];
    if (ki < 0) return;
    const int s0 = start[ki];
    const int s1 = start[ki + 1];
    const int q = threadIdx.x & 3;
    const int g = threadIdx.x >> 2;       // pair group [0,64)

    const float4 a = *reinterpret_cast<const float4*>(z1 + i * RR + q * 4);

    for (int j = s0 + g; j < s1; j += 64) {
        if (key[j] != ki) continue;                   // fill's default stands
        const float s = seg[i * NN + j];              // 4-lane broadcast
        const float seg_eff = s + ((i == j) ? 1.0f : 0.0f);
        if (seg_eff != 0.0f) continue;                // default stands
        const float4 b = *reinterpret_cast<const float4*>(z2 + j * RR + q * 4);
        f32x4 r;
        r.x = a.x * b.x; r.y = a.y * b.y; r.z = a.z * b.z; r.w = a.w * b.w;
        float* op = out + ((size_t)i * NN + j) * RR + q * 4;
        __builtin_nontemporal_store(r, reinterpret_cast<f32x4*>(op));
    }
}

extern "C" void kernel_launch(void* const* d_in, const int* in_sizes, int n_in,
                              void* d_out, int out_size, void* d_ws, size_t ws_size,
                              hipStream_t stream) {
    const float* z1  = (const float*)d_in[0];
    const float* z2  = (const float*)d_in[1];
    const float* seg = (const float*)d_in[2];
    const int* cls   = (const int*)d_in[3];
    const int* batch = (const int*)d_in[4];
    float* out = (float*)d_out;
    int* key   = (int*)d_ws;
    int* start = key + NN;

    frd_fill_kernel<<<FILL_BLOCKS, 256, 0, stream>>>(out);
    frd_prep_kernel<<<(NN + 255) / 256, 256, 0, stream>>>(cls, batch, key, start);
    frd_diag_kernel<<<NN, 256, 0, stream>>>(z1, z2, seg, key, start, out);
}

// Round 17
// 131.046 us; speedup vs baseline: 1.0241x; 1.0241x over previous
//
#include <hip/hip_runtime.h>
#include <cstddef>

#define NN 3072
#define RR 16
#define NB 16
#define FILL_BLOCKS 512
#define FILL_ITERS 288   // NN*NN*4 quads / (FILL_BLOCKS*256 threads) = 288 exactly

typedef float f32x4 __attribute__((ext_vector_type(4)));

// Prologue: key[i] = valid ? batch[i] : -1, plus batch row boundaries
// start[b] = first row with batch >= b (batch sorted). start[NB]=NN.
__global__ void frd_prep_kernel(const int* __restrict__ cls,
                                const int* __restrict__ batch,
                                int* __restrict__ key,
                                int* __restrict__ start) {
    int t = blockIdx.x * blockDim.x + threadIdx.x;
    if (t < NN) {
        int c = cls[t];
        int b = batch[t];
        key[t] = (c != 24 && c != 25 && c != 26) ? b : -1;
        int prev = (t == 0) ? -1 : batch[t - 1];
        for (int bb = prev + 1; bb <= b; ++bb) start[bb] = t;
        if (t == NN - 1)
            for (int bb = b + 1; bb <= NB; ++bb) start[bb] = NN;
    }
}

// Phase 1: pure NT fill, grid-stride (R14 winning structure). A/B this round:
// 512 blocks (2 waves/SIMD) vs R14's 256 — covers single-wave issue bubbles
// while keeping the write-stream count low.
__global__ __launch_bounds__(256)
void frd_fill_kernel(float* __restrict__ out) {
    const int t = blockIdx.x * 256 + threadIdx.x;        // [0, 131072)
    const float d0 = ((t & 3) == 0) ? 1.0f : 0.0f;
    const f32x4 r = {d0, 0.0f, 0.0f, 0.0f};
    float* p = out + (size_t)t * 4;
    const size_t step = (size_t)FILL_BLOCKS * 256 * 4;   // 2 MB in floats
#pragma unroll 8
    for (int it = 0; it < FILL_ITERS; ++it) {
        __builtin_nontemporal_store(r, reinterpret_cast<f32x4*>(p));
        p += step;
    }
}

// Phase 3: overwrite true pairs only. One block per row i (exit if key
// invalid). 4 lanes per pair (lane q writes quad q) -> each written pair is
// one full 64 B line, coalesced across the wave. Sweeps row i's batch range.
__global__ __launch_bounds__(256)
void frd_diag_kernel(const float* __restrict__ z1,
                     const float* __restrict__ z2,
                     const float* __restrict__ seg,
                     const int* __restrict__ key,
                     const int* __restrict__ start,
                     float* __restrict__ out) {
    const int i = blockIdx.x;
    const int ki = key[i];
    if (ki < 0) return;
    const int s0 = start[ki];
    const int s1 = start[ki + 1];
    const int q = threadIdx.x & 3;
    const int g = threadIdx.x >> 2;       // pair group [0,64)

    const float4 a = *reinterpret_cast<const float4*>(z1 + i * RR + q * 4);

    for (int j = s0 + g; j < s1; j += 64) {
        if (key[j] != ki) continue;                   // fill's default stands
        const float s = seg[i * NN + j];              // 4-lane broadcast
        const float seg_eff = s + ((i == j) ? 1.0f : 0.0f);
        if (seg_eff != 0.0f) continue;                // default stands
        const float4 b = *reinterpret_cast<const float4*>(z2 + j * RR + q * 4);
        f32x4 r;
        r.x = a.x * b.x; r.y = a.y * b.y; r.z = a.z * b.z; r.w = a.w * b.w;
        float* op = out + ((size_t)i * NN + j) * RR + q * 4;
        __builtin_nontemporal_store(r, reinterpret_cast<f32x4*>(op));
    }
}

extern "C" void kernel_launch(void* const* d_in, const int* in_sizes, int n_in,
                              void* d_out, int out_size, void* d_ws, size_t ws_size,
                              hipStream_t stream) {
    const float* z1  = (const float*)d_in[0];
    const float* z2  = (const float*)d_in[1];
    const float* seg = (const float*)d_in[2];
    const int* cls   = (const int*)d_in[3];
    const int* batch = (const int*)d_in[4];
    float* out = (float*)d_out;
    int* key   = (int*)d_ws;
    int* start = key + NN;

    frd_fill_kernel<<<FILL_BLOCKS, 256, 0, stream>>>(out);
    frd_prep_kernel<<<(NN + 255) / 256, 256, 0, stream>>>(cls, batch, key, start);
    frd_diag_kernel<<<NN, 256, 0, stream>>>(z1, z2, seg, key, start, out);
}

// Round 18
// 122.069 us; speedup vs baseline: 1.0994x; 1.0735x over previous
//
#include <hip/hip_runtime.h>
#include <cstddef>

#define NN 3072
#define RR 16
#define NB 16
#define FILL_BLOCKS 256
#define FILL_THREADS 1024
#define FILL_ITERS 144   // NN*NN*4 quads / (256 blk * 1024 thr) = 144 exactly

typedef float f32x4 __attribute__((ext_vector_type(4)));

// Prologue: key[i] = valid ? batch[i] : -1, plus batch row boundaries
// start[b] = first row with batch >= b (batch sorted). start[NB]=NN.
__global__ void frd_prep_kernel(const int* __restrict__ cls,
                                const int* __restrict__ batch,
                                int* __restrict__ key,
                                int* __restrict__ start) {
    int t = blockIdx.x * blockDim.x + threadIdx.x;
    if (t < NN) {
        int c = cls[t];
        int b = batch[t];
        key[t] = (c != 24 && c != 25 && c != 26) ? b : -1;
        int prev = (t == 0) ? -1 : batch[t - 1];
        for (int bb = prev + 1; bb <= b; ++bb) start[bb] = t;
        if (t == NN - 1)
            for (int bb = b + 1; bb <= NB; ++bb) start[bb] = NN;
    }
}

// Phase 1: pure NT fill, grid-stride, 256 blocks (1/CU — proven optimal
// stream count) but 1024 threads/block: 4x wave-level concurrency per CU to
// cover single-wave issue/drain bubbles WITHOUT adding address streams.
// Each block-iteration writes one contiguous 16 KB chunk.
__global__ __launch_bounds__(FILL_THREADS)
void frd_fill_kernel(float* __restrict__ out) {
    const int t = blockIdx.x * FILL_THREADS + threadIdx.x;  // [0, 262144)
    const float d0 = ((t & 3) == 0) ? 1.0f : 0.0f;
    const f32x4 r = {d0, 0.0f, 0.0f, 0.0f};
    float* p = out + (size_t)t * 4;
    const size_t step = (size_t)FILL_BLOCKS * FILL_THREADS * 4;  // 4 MB in floats
#pragma unroll 8
    for (int it = 0; it < FILL_ITERS; ++it) {
        __builtin_nontemporal_store(r, reinterpret_cast<f32x4*>(p));
        p += step;
    }
}

// Phase 3: overwrite true pairs only. One block per row i (exit if key
// invalid). 4 lanes per pair (lane q writes quad q) -> each written pair is
// one full 64 B line, coalesced across the wave. Sweeps row i's batch range.
__global__ __launch_bounds__(256)
void frd_diag_kernel(const float* __restrict__ z1,
                     const float* __restrict__ z2,
                     const float* __restrict__ seg,
                     const int* __restrict__ key,
                     const int* __restrict__ start,
                     float* __restrict__ out) {
    const int i = blockIdx.x;
    const int ki = key[i];
    if (ki < 0) return;
    const int s0 = start[ki];
    const int s1 = start[ki + 1];
    const int q = threadIdx.x & 3;
    const int g = threadIdx.x >> 2;       // pair group [0,64)

    const float4 a = *reinterpret_cast<const float4*>(z1 + i * RR + q * 4);

    for (int j = s0 + g; j < s1; j += 64) {
        if (key[j] != ki) continue;                   // fill's default stands
        const float s = seg[i * NN + j];              // 4-lane broadcast
        const float seg_eff = s + ((i == j) ? 1.0f : 0.0f);
        if (seg_eff != 0.0f) continue;                // default stands
        const float4 b = *reinterpret_cast<const float4*>(z2 + j * RR + q * 4);
        f32x4 r;
        r.x = a.x * b.x; r.y = a.y * b.y; r.z = a.z * b.z; r.w = a.w * b.w;
        float* op = out + ((size_t)i * NN + j) * RR + q * 4;
        __builtin_nontemporal_store(r, reinterpret_cast<f32x4*>(op));
    }
}

extern "C" void kernel_launch(void* const* d_in, const int* in_sizes, int n_in,
                              void* d_out, int out_size, void* d_ws, size_t ws_size,
                              hipStream_t stream) {
    const float* z1  = (const float*)d_in[0];
    const float* z2  = (const float*)d_in[1];
    const float* seg = (const float*)d_in[2];
    const int* cls   = (const int*)d_in[3];
    const int* batch = (const int*)d_in[4];
    float* out = (float*)d_out;
    int* key   = (int*)d_ws;
    int* start = key + NN;

    frd_fill_kernel<<<FILL_BLOCKS, FILL_THREADS, 0, stream>>>(out);
    frd_prep_kernel<<<(NN + 255) / 256, 256, 0, stream>>>(cls, batch, key, start);
    frd_diag_kernel<<<NN, 256, 0, stream>>>(z1, z2, seg, key, start, out);
}

// Round 19
// 120.301 us; speedup vs baseline: 1.1156x; 1.0147x over previous
//
#include <hip/hip_runtime.h>
#include <cstddef>

#define NN 3072
#define RR 16
#define NB 16
#define FILL_BLOCKS 256
#define FILL_ITERS 576   // NN*NN*4 quads / (FILL_BLOCKS*256 threads) = 576 exactly

typedef float f32x4 __attribute__((ext_vector_type(4)));

// Prologue: key[i] = valid ? batch[i] : -1, plus batch row boundaries
// start[b] = first row with batch >= b (batch sorted). start[NB]=NN.
__global__ void frd_prep_kernel(const int* __restrict__ cls,
                                const int* __restrict__ batch,
                                int* __restrict__ key,
                                int* __restrict__ start) {
    int t = blockIdx.x * blockDim.x + threadIdx.x;
    if (t < NN) {
        int c = cls[t];
        int b = batch[t];
        key[t] = (c != 24 && c != 25 && c != 26) ? b : -1;
        int prev = (t == 0) ? -1 : batch[t - 1];
        for (int bb = prev + 1; bb <= b; ++bb) start[bb] = t;
        if (t == NN - 1)
            for (int bb = b + 1; bb <= NB; ++bb) start[bb] = NN;
    }
}

// Fused kernel. Blocks [0, FILL_BLOCKS): masked NT fill in the proven R14
// shape (grid-stride, 1 block/CU, 1 wave/SIMD) — writes the default to every
// pair EXCEPT key-match pairs (ki>=0 && ki==kj). Blocks [FILL_BLOCKS,
// FILL_BLOCKS+NN): diag row blocks — write exactly the key-match pairs
// (product if seg_eff==0 else default). The two sets are disjoint at 64 B
// line granularity -> race-free in one launch; diag blocks backfill spare
// wave slots and drain under the fill's first ~10 us.
__global__ __launch_bounds__(256)
void frd_fused_kernel(const float* __restrict__ z1,
                      const float* __restrict__ z2,
                      const float* __restrict__ seg,
                      const int* __restrict__ key,
                      const int* __restrict__ start,
                      float* __restrict__ out) {
    const int bid = blockIdx.x;
    if (bid < FILL_BLOCKS) {
        // ---- masked fill ----
        const int t = bid * 256 + threadIdx.x;           // [0, 65536)
        const float d0 = ((t & 3) == 0) ? 1.0f : 0.0f;
        const f32x4 r = {d0, 0.0f, 0.0f, 0.0f};
        int quad = t;
        const int step = FILL_BLOCKS * 256;              // 65536 quads / sweep
#pragma unroll 8
        for (int it = 0; it < FILL_ITERS; ++it) {
            const int pair = quad >> 2;                  // 4 lanes share a pair
            const int i = pair / NN;                     // magic-mul
            const int j = pair - i * NN;
            const int ki = key[i];                       // L1-resident (12 KB)
            const int kj = key[j];
            const bool skip = (ki >= 0) && (ki == kj);   // diag writes these
            if (!skip)                                   // whole-line granularity
                __builtin_nontemporal_store(r, reinterpret_cast<f32x4*>(out + (size_t)quad * 4));
            quad += step;
        }
    } else {
        // ---- diag row ----
        const int i = bid - FILL_BLOCKS;
        const int ki = key[i];
        if (ki < 0) return;
        const int s0 = start[ki];
        const int s1 = start[ki + 1];
        const int q = threadIdx.x & 3;
        const int g = threadIdx.x >> 2;                  // pair group [0,64)

        const float4 a = *reinterpret_cast<const float4*>(z1 + i * RR + q * 4);
        const float d0 = (q == 0) ? 1.0f : 0.0f;

        for (int j = s0 + g; j < s1; j += 64) {
            if (key[j] != ki) continue;                  // fill wrote this pair
            const float s = seg[i * NN + j];             // 4-lane broadcast
            const float seg_eff = s + ((i == j) ? 1.0f : 0.0f);
            f32x4 r;
            if (seg_eff == 0.0f) {
                const float4 b = *reinterpret_cast<const float4*>(z2 + j * RR + q * 4);
                r.x = a.x * b.x; r.y = a.y * b.y; r.z = a.z * b.z; r.w = a.w * b.w;
            } else {
                r.x = d0; r.y = 0.0f; r.z = 0.0f; r.w = 0.0f;
            }
            float* op = out + ((size_t)i * NN + j) * RR + q * 4;
            __builtin_nontemporal_store(r, reinterpret_cast<f32x4*>(op));
        }
    }
}

extern "C" void kernel_launch(void* const* d_in, const int* in_sizes, int n_in,
                              void* d_out, int out_size, void* d_ws, size_t ws_size,
                              hipStream_t stream) {
    const float* z1  = (const float*)d_in[0];
    const float* z2  = (const float*)d_in[1];
    const float* seg = (const float*)d_in[2];
    const int* cls   = (const int*)d_in[3];
    const int* batch = (const int*)d_in[4];
    float* out = (float*)d_out;
    int* key   = (int*)d_ws;
    int* start = key + NN;

    frd_prep_kernel<<<(NN + 255) / 256, 256, 0, stream>>>(cls, batch, key, start);
    frd_fused_kernel<<<FILL_BLOCKS + NN, 256, 0, stream>>>(z1, z2, seg, key, start, out);
}

// Round 20
// 110.445 us; speedup vs baseline: 1.2151x; 1.0892x over previous
//
#include <hip/hip_runtime.h>
#include <cstddef>

#define NN 3072
#define RR 16
#define NB 16
#define FILL_BLOCKS 128
#define FILL_ITERS 1152  // NN*NN*4 quads / (FILL_BLOCKS*256 threads) = 1152 exactly

typedef float f32x4 __attribute__((ext_vector_type(4)));

// Prologue: key[i] = valid ? batch[i] : -1, plus batch row boundaries
// start[b] = first row with batch >= b (batch sorted). start[NB]=NN.
__global__ void frd_prep_kernel(const int* __restrict__ cls,
                                const int* __restrict__ batch,
                                int* __restrict__ key,
                                int* __restrict__ start) {
    int t = blockIdx.x * blockDim.x + threadIdx.x;
    if (t < NN) {
        int c = cls[t];
        int b = batch[t];
        key[t] = (c != 24 && c != 25 && c != 26) ? b : -1;
        int prev = (t == 0) ? -1 : batch[t - 1];
        for (int bb = prev + 1; bb <= b; ++bb) start[bb] = t;
        if (t == NN - 1)
            for (int bb = b + 1; bb <= NB; ++bb) start[bb] = NN;
    }
}

// Phase 1: pure NT fill, grid-stride (R14 winning structure). Final A/B:
// 128 blocks (half a block per CU-pair, half the write-stream count of the
// 256-block optimum) — probing below the known peak of the concurrency curve.
__global__ __launch_bounds__(256)
void frd_fill_kernel(float* __restrict__ out) {
    const int t = blockIdx.x * 256 + threadIdx.x;        // [0, 32768)
    const float d0 = ((t & 3) == 0) ? 1.0f : 0.0f;
    const f32x4 r = {d0, 0.0f, 0.0f, 0.0f};
    float* p = out + (size_t)t * 4;
    const size_t step = (size_t)FILL_BLOCKS * 256 * 4;   // 512 KB in floats
#pragma unroll 8
    for (int it = 0; it < FILL_ITERS; ++it) {
        __builtin_nontemporal_store(r, reinterpret_cast<f32x4*>(p));
        p += step;
    }
}

// Phase 3: overwrite true pairs only. One block per row i (exit if key
// invalid). 4 lanes per pair (lane q writes quad q) -> each written pair is
// one full 64 B line, coalesced across the wave. Sweeps row i's batch range.
__global__ __launch_bounds__(256)
void frd_diag_kernel(const float* __restrict__ z1,
                     const float* __restrict__ z2,
                     const float* __restrict__ seg,
                     const int* __restrict__ key,
                     const int* __restrict__ start,
                     float* __restrict__ out) {
    const int i = blockIdx.x;
    const int ki = key[i];
    if (ki < 0) return;
    const int s0 = start[ki];
    const int s1 = start[ki + 1];
    const int q = threadIdx.x & 3;
    const int g = threadIdx.x >> 2;       // pair group [0,64)

    const float4 a = *reinterpret_cast<const float4*>(z1 + i * RR + q * 4);

    for (int j = s0 + g; j < s1; j += 64) {
        if (key[j] != ki) continue;                   // fill's default stands
        const float s = seg[i * NN + j];              // 4-lane broadcast
        const float seg_eff = s + ((i == j) ? 1.0f : 0.0f);
        if (seg_eff != 0.0f) continue;                // default stands
        const float4 b = *reinterpret_cast<const float4*>(z2 + j * RR + q * 4);
        f32x4 r;
        r.x = a.x * b.x; r.y = a.y * b.y; r.z = a.z * b.z; r.w = a.w * b.w;
        float* op = out + ((size_t)i * NN + j) * RR + q * 4;
        __builtin_nontemporal_store(r, reinterpret_cast<f32x4*>(op));
    }
}

extern "C" void kernel_launch(void* const* d_in, const int* in_sizes, int n_in,
                              void* d_out, int out_size, void* d_ws, size_t ws_size,
                              hipStream_t stream) {
    const float* z1  = (const float*)d_in[0];
    const float* z2  = (const float*)d_in[1];
    const float* seg = (const float*)d_in[2];
    const int* cls   = (const int*)d_in[3];
    const int* batch = (const int*)d_in[4];
    float* out = (float*)d_out;
    int* key   = (int*)d_ws;
    int* start = key + NN;

    frd_fill_kernel<<<FILL_BLOCKS, 256, 0, stream>>>(out);
    frd_prep_kernel<<<(NN + 255) / 256, 256, 0, stream>>>(cls, batch, key, start);
    frd_diag_kernel<<<NN, 256, 0, stream>>>(z1, z2, seg, key, start, out);
}

// Round 21
// 106.260 us; speedup vs baseline: 1.2630x; 1.0394x over previous
//
#include <hip/hip_runtime.h>
#include <cstddef>

#define NN 3072
#define RR 16
#define NB 16
#define FILL_BLOCKS 64
#define FILL_ITERS 2304  // NN*NN*4 quads / (FILL_BLOCKS*256 threads) = 2304 exactly

typedef float f32x4 __attribute__((ext_vector_type(4)));

// Prologue: key[i] = valid ? batch[i] : -1, plus batch row boundaries
// start[b] = first row with batch >= b (batch sorted). start[NB]=NN.
__global__ void frd_prep_kernel(const int* __restrict__ cls,
                                const int* __restrict__ batch,
                                int* __restrict__ key,
                                int* __restrict__ start) {
    int t = blockIdx.x * blockDim.x + threadIdx.x;
    if (t < NN) {
        int c = cls[t];
        int b = batch[t];
        key[t] = (c != 24 && c != 25 && c != 26) ? b : -1;
        int prev = (t == 0) ? -1 : batch[t - 1];
        for (int bb = prev + 1; bb <= b; ++bb) start[bb] = t;
        if (t == NN - 1)
            for (int bb = b + 1; bb <= NB; ++bb) start[bb] = NN;
    }
}

// Phase 1: pure NT fill, grid-stride. Concurrency sweep continues: 64 blocks
// (curve so far: 2048->4.1, 512->4.9, 256->5.8, 128->6.0 TB/s — monotone
// improving as write-stream count drops; probing for the bottom).
__global__ __launch_bounds__(256)
void frd_fill_kernel(float* __restrict__ out) {
    const int t = blockIdx.x * 256 + threadIdx.x;        // [0, 16384)
    const float d0 = ((t & 3) == 0) ? 1.0f : 0.0f;
    const f32x4 r = {d0, 0.0f, 0.0f, 0.0f};
    float* p = out + (size_t)t * 4;
    const size_t step = (size_t)FILL_BLOCKS * 256 * 4;   // 256 KB in floats
#pragma unroll 8
    for (int it = 0; it < FILL_ITERS; ++it) {
        __builtin_nontemporal_store(r, reinterpret_cast<f32x4*>(p));
        p += step;
    }
}

// Phase 3: overwrite true pairs only. One block per row i (exit if key
// invalid). 4 lanes per pair (lane q writes quad q) -> each written pair is
// one full 64 B line, coalesced across the wave. Sweeps row i's batch range.
__global__ __launch_bounds__(256)
void frd_diag_kernel(const float* __restrict__ z1,
                     const float* __restrict__ z2,
                     const float* __restrict__ seg,
                     const int* __restrict__ key,
                     const int* __restrict__ start,
                     float* __restrict__ out) {
    const int i = blockIdx.x;
    const int ki = key[i];
    if (ki < 0) return;
    const int s0 = start[ki];
    const int s1 = start[ki + 1];
    const int q = threadIdx.x & 3;
    const int g = threadIdx.x >> 2;       // pair group [0,64)

    const float4 a = *reinterpret_cast<const float4*>(z1 + i * RR + q * 4);

    for (int j = s0 + g; j < s1; j += 64) {
        if (key[j] != ki) continue;                   // fill's default stands
        const float s = seg[i * NN + j];              // 4-lane broadcast
        const float seg_eff = s + ((i == j) ? 1.0f : 0.0f);
        if (seg_eff != 0.0f) continue;                // default stands
        const float4 b = *reinterpret_cast<const float4*>(z2 + j * RR + q * 4);
        f32x4 r;
        r.x = a.x * b.x; r.y = a.y * b.y; r.z = a.z * b.z; r.w = a.w * b.w;
        float* op = out + ((size_t)i * NN + j) * RR + q * 4;
        __builtin_nontemporal_store(r, reinterpret_cast<f32x4*>(op));
    }
}

extern "C" void kernel_launch(void* const* d_in, const int* in_sizes, int n_in,
                              void* d_out, int out_size, void* d_ws, size_t ws_size,
                              hipStream_t stream) {
    const float* z1  = (const float*)d_in[0];
    const float* z2  = (const float*)d_in[1];
    const float* seg = (const float*)d_in[2];
    const int* cls   = (const int*)d_in[3];
    const int* batch = (const int*)d_in[4];
    float* out = (float*)d_out;
    int* key   = (int*)d_ws;
    int* start = key + NN;

    frd_fill_kernel<<<FILL_BLOCKS, 256, 0, stream>>>(out);
    frd_prep_kernel<<<(NN + 255) / 256, 256, 0, stream>>>(cls, batch, key, start);
    frd_diag_kernel<<<NN, 256, 0, stream>>>(z1, z2, seg, key, start, out);
}